// Round 7
// baseline (81.347 us; speedup 1.0000x reference)
//
#include <hip/hip_runtime.h>

#define BB 8
#define CC 128
#define HH 64
#define WW 64
#define K2 9
#define NOFF 18
#define HW 4096          // HH*WW
#define NPIX 32768       // BB*HW
#define NQ 4             // channel quarter-groups (blockIdx.y)
#define WPB 4            // waves per block
#define CPW 8            // channels per wave
#define WPAD 20          // padded weight row (18 used, 80 B stride)

// ---------------------------------------------------------------------------
// K-1: transpose offset weights [18][1152] -> wTp[k=(c,j)][WPAD] so the 18
// output weights per k are contiguous (72 B, 16B-aligned) -> wide s_loads.
// ---------------------------------------------------------------------------
__global__ __launch_bounds__(256) void wtrans_kernel(
    const float* __restrict__ offw, float* __restrict__ wTp)
{
    int i = blockIdx.x * 256 + threadIdx.x;
    if (i >= NOFF * CC * 9) return;
    int k = i / NOFF, o = i - k * NOFF;
    wTp[k * WPAD + o] = offw[(size_t)o * CC * 9 + k];
}

// ---------------------------------------------------------------------------
// K1: offset-conv partials, max-TLP variant. Grid (512, 4): b = x&7
// (XCD-local), h = x>>3. Block = 256 thr = 4 waves; wave wv owns channels
// q*32 + wv*8..+7 and ONE pixel row (lane = w). Live set ~50 VGPR
// (acc[18] + xr[3][3]) -> launch_bounds(256,6): 6 blocks/CU, 24 waves/CU.
// Per (cc,jj): contiguous 72 B uniform weight run (s_load) feeds 18 v_fmac;
// cc unrolled x2 so next channel's loads issue under current FMAs.
// ---------------------------------------------------------------------------
__global__ __launch_bounds__(256, 6) void offset_partial_kernel(
    const float* __restrict__ x, const float* __restrict__ wTp,
    float* __restrict__ part)
{
    __shared__ float sred[NOFF * WPB * 64];   // 18 KB
    int jx = blockIdx.x;           // 0..511
    int b = jx & 7;
    int h = jx >> 3;               // 0..63
    int q = blockIdx.y;            // 0..3
    int tid = threadIdx.x;
    int w = tid & 63;
    int wv = __builtin_amdgcn_readfirstlane(tid >> 6);  // 0..3
    int cbase = q * 32 + wv * CPW;

    float acc[NOFF];
#pragma unroll
    for (int o = 0; o < NOFF; ++o) acc[o] = 0.f;

#pragma unroll 2
    for (int cc = 0; cc < CPW; ++cc) {
        int c = cbase + cc;
        const float* xp = x + ((size_t)(b * CC + c)) * HW;
        float xr[3][3];
#pragma unroll
        for (int rr = 0; rr < 3; ++rr) {
            int hh = h + rr - 1;
            bool hok = (unsigned)hh < HH;
#pragma unroll
            for (int dc = 0; dc < 3; ++dc) {
                int ww2 = w + dc - 1;
                bool ok = hok && ((unsigned)ww2 < WW);
                xr[rr][dc] = ok ? xp[hh * WW + ww2] : 0.f;
            }
        }
        const float* wrow = wTp + (size_t)c * 9 * WPAD;
#pragma unroll
        for (int jj = 0; jj < 9; ++jj) {
            const float xv = xr[jj / 3][jj % 3];
            const float* wp = wrow + jj * WPAD;     // uniform -> s_load
#pragma unroll
            for (int o = 0; o < NOFF; ++o)
                acc[o] = fmaf(xv, wp[o], acc[o]);
        }
    }

    // reduce over 4 waves
#pragma unroll
    for (int o = 0; o < NOFF; ++o)
        sred[(o * WPB + wv) * 64 + w] = acc[o];
    __syncthreads();
    for (int item = tid; item < NOFF * 64; item += 256) {
        int o = item >> 6, p = item & 63;
        float s = 0.f;
#pragma unroll
        for (int u = 0; u < WPB; ++u) s += sred[(o * WPB + u) * 64 + p];
        part[((size_t)(q * NOFF + o)) * NPIX + b * HW + h * 64 + p] = s;
    }
}

// ---------------------------------------------------------------------------
// K1b: sum 4 quarter-partials, add bias, transform to pixel coords.
// ---------------------------------------------------------------------------
__global__ __launch_bounds__(256) void reduce_grid_kernel(
    const float* __restrict__ part, const float* __restrict__ offb,
    float2* __restrict__ grid2)
{
    int pixel = blockIdx.x * 256 + threadIdx.x;
    int t = blockIdx.y;
    float sx = offb[t], sy = offb[t + K2];
#pragma unroll
    for (int q = 0; q < NQ; ++q) {
        sx += part[((size_t)(q * NOFF + t)) * NPIX + pixel];
        sy += part[((size_t)(q * NOFF + t + K2)) * NPIX + pixel];
    }
    int w = pixel & 63, h = (pixel >> 6) & 63, b = pixel >> 12;
    float base_x = -1.f + (2.f / (WW - 1)) * (float)w;
    float base_y = -1.f + (2.f / (HH - 1)) * (float)h;
    float gx = ((sx + base_x + 1.f) * (float)WW - 1.f) * 0.5f;
    float gy = ((sy + base_y + 1.f) * (float)HH - 1.f) * 0.5f;
    grid2[((size_t)(b * K2 + t)) * HW + (pixel & (HW - 1))] = make_float2(gx, gy);
}

// ---------------------------------------------------------------------------
// K0: transpose x [B,C,H,W] -> xT [B,H*W,C]
// ---------------------------------------------------------------------------
__global__ __launch_bounds__(256) void transpose_kernel(
    const float* __restrict__ x, float* __restrict__ xT)
{
    __shared__ float tile[32][33];
    int b  = blockIdx.z;
    int c0 = blockIdx.y * 32;
    int p0 = blockIdx.x * 32;
    int tx = threadIdx.x;
    int ty = threadIdx.y;
#pragma unroll
    for (int i = 0; i < 4; ++i)
        tile[ty + i * 8][tx] = x[((size_t)(b * CC + c0 + ty + i * 8)) * HW + p0 + tx];
    __syncthreads();
#pragma unroll
    for (int i = 0; i < 4; ++i)
        xT[((size_t)b * HW + p0 + ty + i * 8) * CC + c0 + tx] = tile[tx][ty + i * 8];
}

// ---------------------------------------------------------------------------
// K2: bilinear sample + tap-weighted sum, float4 channel packing.
// ---------------------------------------------------------------------------
__global__ __launch_bounds__(256) void sample_kernel(
    const float* __restrict__ xT, const float2* __restrict__ grid2,
    const float* __restrict__ wk, float* __restrict__ out)
{
    __shared__ float4 recW[144];
    __shared__ int2   recI[144];
    __shared__ float  swkT[K2 * CC];
    __shared__ float  acc_s[16 * 132];

    int j = blockIdx.x;            // 0..2047
    int b = j & 7;
    int rem_base = (j >> 3) * 16;
    int h  = rem_base >> 6;
    int w0 = rem_base & 63;
    int tid = threadIdx.x;

    for (int i = tid; i < K2 * CC; i += 256) {
        int c = i / 9, t = i - c * 9;
        swkT[t * CC + c] = wk[i];
    }

    if (tid < 144) {
        int slot = tid & 15;
        int tap  = tid >> 4;
        float2 g = grid2[((size_t)(b * K2 + tap)) * HW + rem_base + slot];
        float gx = g.x, gy = g.y;
        float x0f = floorf(gx), y0f = floorf(gy);
        float wx1 = gx - x0f, wx0 = 1.f - wx1;
        float wy1 = gy - y0f, wy0 = 1.f - wy1;
        int ix0 = (int)x0f, iy0 = (int)y0f;
        int ix1 = ix0 + 1,  iy1 = iy0 + 1;
        float ax0 = ((unsigned)ix0 < WW) ? wx0 : 0.f;
        float ax1 = ((unsigned)ix1 < WW) ? wx1 : 0.f;
        float ay0 = ((unsigned)iy0 < HH) ? wy0 : 0.f;
        float ay1 = ((unsigned)iy1 < HH) ? wy1 : 0.f;
        int cx0 = min(max(ix0, 0), WW - 1), cx1 = min(max(ix1, 0), WW - 1);
        int cy0 = min(max(iy0, 0), HH - 1), cy1 = min(max(iy1, 0), HH - 1);
        int o00 = cy0 * WW + cx0, o10 = cy0 * WW + cx1;
        int o01 = cy1 * WW + cx0, o11 = cy1 * WW + cx1;
        recW[tid] = make_float4(ax0 * ay0, ax1 * ay0, ax0 * ay1, ax1 * ay1);
        recI[tid] = make_int2(o00 | (o10 << 16), o01 | (o11 << 16));
    }
    __syncthreads();

    int c4  = (tid & 31) * 4;
    int sl0 = tid >> 5;

    float4 wk4[K2];
#pragma unroll
    for (int t = 0; t < K2; ++t)
        wk4[t] = *(const float4*)&swkT[t * CC + c4];

    const float* xb = xT + (size_t)b * HW * CC;

#pragma unroll
    for (int pp = 0; pp < 2; ++pp) {
        int slot = pp * 8 + sl0;
        float4 acc = make_float4(0.f, 0.f, 0.f, 0.f);
#pragma unroll
        for (int t = 0; t < K2; ++t) {
            int r = t * 16 + slot;
            float4 wv = recW[r];
            int2   iv = recI[r];
            float4 v00 = *(const float4*)(xb + ((iv.x & 0xFFFF) << 7) + c4);
            float4 v10 = *(const float4*)(xb + ((iv.x >> 16)     << 7) + c4);
            float4 v01 = *(const float4*)(xb + ((iv.y & 0xFFFF) << 7) + c4);
            float4 v11 = *(const float4*)(xb + ((iv.y >> 16)     << 7) + c4);
            float bx0 = fmaf(v00.x, wv.x, fmaf(v10.x, wv.y, fmaf(v01.x, wv.z, v11.x * wv.w)));
            float bx1 = fmaf(v00.y, wv.x, fmaf(v10.y, wv.y, fmaf(v01.y, wv.z, v11.y * wv.w)));
            float bx2 = fmaf(v00.z, wv.x, fmaf(v10.z, wv.y, fmaf(v01.z, wv.z, v11.z * wv.w)));
            float bx3 = fmaf(v00.w, wv.x, fmaf(v10.w, wv.y, fmaf(v01.w, wv.z, v11.w * wv.w)));
            acc.x = fmaf(bx0, wk4[t].x, acc.x);
            acc.y = fmaf(bx1, wk4[t].y, acc.y);
            acc.z = fmaf(bx2, wk4[t].z, acc.z);
            acc.w = fmaf(bx3, wk4[t].w, acc.w);
        }
        *(float4*)&acc_s[slot * 132 + c4] = acc;
    }
    __syncthreads();
#pragma unroll
    for (int r = 0; r < 8; ++r) {
        int cs   = r * 16 + (tid >> 4);
        int wloc = tid & 15;
        out[((size_t)(b * CC + cs)) * HW + h * WW + w0 + wloc] = acc_s[wloc * 132 + cs];
    }
}

// ---------------------------------------------------------------------------
// Fallback (round-1 pipeline, needs only 2.36 MB ws) — defensive only.
// ---------------------------------------------------------------------------
__global__ __launch_bounds__(256) void offset_grid_kernel_fb(
    const float* __restrict__ x, const float* __restrict__ offw,
    const float* __restrict__ offb, float* __restrict__ grid)
{
    int idx = blockIdx.x * blockDim.x + threadIdx.x;
    if (idx >= NPIX) return;
    int w = idx & 63, h = (idx >> 6) & 63, b = idx >> 12;
    float acc[NOFF];
#pragma unroll
    for (int o = 0; o < NOFF; ++o) acc[o] = offb[o];
    for (int c = 0; c < CC; ++c) {
        const float* xp = x + ((size_t)(b * CC + c)) * HW;
        float xv[9];
#pragma unroll
        for (int dh = -1; dh <= 1; ++dh)
#pragma unroll
            for (int dw = -1; dw <= 1; ++dw) {
                int hh = h + dh, ww2 = w + dw;
                float v = 0.f;
                if (hh >= 0 && hh < HH && ww2 >= 0 && ww2 < WW) v = xp[hh * WW + ww2];
                xv[(dh + 1) * 3 + (dw + 1)] = v;
            }
#pragma unroll
        for (int o = 0; o < NOFF; ++o) {
            const float* wp = offw + (size_t)(o * CC + c) * 9;
#pragma unroll
            for (int jj = 0; jj < 9; ++jj) acc[o] = fmaf(xv[jj], wp[jj], acc[o]);
        }
    }
    float base_x = -1.f + (2.f / (WW - 1)) * (float)w;
    float base_y = -1.f + (2.f / (HH - 1)) * (float)h;
#pragma unroll
    for (int t = 0; t < K2; ++t) {
        float gx = ((acc[t]      + base_x + 1.f) * (float)WW - 1.f) * 0.5f;
        float gy = ((acc[K2 + t] + base_y + 1.f) * (float)HH - 1.f) * 0.5f;
        size_t gi = ((((size_t)b * K2 + t) * HH + h) * WW + w) * 2;
        grid[gi] = gx; grid[gi + 1] = gy;
    }
}

__global__ __launch_bounds__(256) void sample_kernel_fb(
    const float* __restrict__ x, const float* __restrict__ grid,
    const float* __restrict__ wk, float* __restrict__ out)
{
    int idx = blockIdx.x * blockDim.x + threadIdx.x;
    if (idx >= BB * CC * HW) return;
    int w = idx & 63, h = (idx >> 6) & 63;
    int c = (idx / HW) & 127, b = idx / (CC * HW);
    const float* xp = x + ((size_t)(b * CC + c)) * HW;
    const float2* gp = (const float2*)grid;
    float acc = 0.f;
#pragma unroll
    for (int t = 0; t < K2; ++t) {
        float2 g = gp[(((size_t)b * K2 + t)) * HW + h * WW + w];
        float gx = g.x, gy = g.y;
        float x0f = floorf(gx), y0f = floorf(gy);
        float wx1 = gx - x0f, wx0 = 1.f - wx1;
        float wy1 = gy - y0f, wy0 = 1.f - wy1;
        int ix0 = (int)x0f, iy0 = (int)y0f;
        int ix1 = ix0 + 1,  iy1 = iy0 + 1;
        float v00 = 0.f, v10 = 0.f, v01 = 0.f, v11 = 0.f;
        if ((unsigned)iy0 < HH) {
            const float* row = xp + (size_t)iy0 * WW;
            if ((unsigned)ix0 < WW) v00 = row[ix0];
            if ((unsigned)ix1 < WW) v10 = row[ix1];
        }
        if ((unsigned)iy1 < HH) {
            const float* row = xp + (size_t)iy1 * WW;
            if ((unsigned)ix0 < WW) v01 = row[ix0];
            if ((unsigned)ix1 < WW) v11 = row[ix1];
        }
        float bil = v00 * (wx0 * wy0) + v10 * (wx1 * wy0)
                  + v01 * (wx0 * wy1) + v11 * (wx1 * wy1);
        acc = fmaf(bil, wk[c * K2 + t], acc);
    }
    out[idx] = acc;
}

extern "C" void kernel_launch(void* const* d_in, const int* in_sizes, int n_in,
                              void* d_out, int out_size, void* d_ws, size_t ws_size,
                              hipStream_t stream) {
    const float* x    = (const float*)d_in[0];
    const float* offw = (const float*)d_in[1];
    const float* offb = (const float*)d_in[2];
    const float* wwk  = (const float*)d_in[3];
    float* out = (float*)d_out;

    const size_t GRID_BYTES = (size_t)NPIX * K2 * 2 * sizeof(float);   // 2.36 MB
    const size_t XT_BYTES   = (size_t)NPIX * CC * sizeof(float);       // 16.8 MB
    const size_t NEED = GRID_BYTES + XT_BYTES;                         // 19.2 MB

    if (ws_size < NEED) {
        float* grid = (float*)d_ws;
        hipLaunchKernelGGL(offset_grid_kernel_fb, dim3(NPIX / 256), dim3(256),
                           0, stream, x, offw, offb, grid);
        hipLaunchKernelGGL(sample_kernel_fb, dim3((BB * CC * HW) / 256), dim3(256),
                           0, stream, x, grid, wwk, out);
        return;
    }

    // ws layout:
    //   [0, 2.36 MB)    : wTp (92 KB, dead after offset_partial) then grid2
    //   [2.36, 19.2 MB) : part (9.4 MB, dead after reduce) then xT (16.8 MB)
    float2* grid2 = (float2*)d_ws;
    float*  wTp   = (float*)d_ws;
    float*  region = (float*)((char*)d_ws + GRID_BYTES);
    float*  part = region;
    float*  xT   = region;

    hipLaunchKernelGGL(wtrans_kernel, dim3((NOFF * CC * 9 + 255) / 256), dim3(256),
                       0, stream, offw, wTp);
    hipLaunchKernelGGL(offset_partial_kernel, dim3(512, NQ), dim3(256),
                       0, stream, x, wTp, part);
    hipLaunchKernelGGL(reduce_grid_kernel, dim3(NPIX / 256, K2), dim3(256),
                       0, stream, part, offb, grid2);
    hipLaunchKernelGGL(transpose_kernel, dim3(HW / 32, CC / 32, BB), dim3(32, 8),
                       0, stream, x, xT);
    hipLaunchKernelGGL(sample_kernel, dim3(NPIX / 16), dim3(256),
                       0, stream, xT, grid2, wwk, out);
}

// Round 8
// 65.372 us; speedup vs baseline: 1.2444x; 1.2444x over previous
//
#include <hip/hip_runtime.h>

#define BB 8
#define CC 128
#define HH 64
#define WW 64
#define K2 9
#define NOFF 18
#define HW 4096          // HH*WW
#define NPIX 32768       // BB*HW
#define NQ 4             // channel quarter-groups
#define ROWS 2           // output rows per lane
#define WPB 4            // waves per block
#define CPW 8            // channels per wave
#define WPAD 20          // padded weight row (18 used, 80 B stride)

#define OFF_BLOCKS 1024  // 256 row-groups x 4 quarters
#define TR_BLOCKS  4096  // 128 p-tiles x 4 c-tiles x 8 b

// ---------------------------------------------------------------------------
// K-1: transpose offset weights [18][1152] -> wTp[k=(c,j)][WPAD]: the 18
// output weights per k are contiguous (72 B, 16B-aligned) -> wide s_loads.
// ---------------------------------------------------------------------------
__global__ __launch_bounds__(256) void wtrans_kernel(
    const float* __restrict__ offw, float* __restrict__ wTp)
{
    int i = blockIdx.x * 256 + threadIdx.x;
    if (i >= NOFF * CC * 9) return;
    int k = i / NOFF, o = i - k * NOFF;
    wTp[k * WPAD + o] = offw[(size_t)o * CC * 9 + k];
}

// ---------------------------------------------------------------------------
// K1: HORIZONTALLY FUSED offset-conv partials + x transpose.
//   blocks [0, OFF_BLOCKS)              : offset-conv role
//   blocks [OFF_BLOCKS, +TR_BLOCKS)     : transpose role (HBM-heavy, fills
//                                         the offset blocks' stall cycles)
// Offset role: block = 2 pixel rows x 4 waves (8 ch each, quarter q).
// Per cc: 4 coalesced row loads (uniform h-bounds branch); left/right
// neighbors via __shfl_up/down (lane = w spans the row; w-edges are lane
// edges) -> 3x fewer VMEM ops, no per-load cndmask. Weights: contiguous
// 72 B uniform runs from wTp (s_load). LDS reduce over waves -> part.
// ---------------------------------------------------------------------------
__global__ __launch_bounds__(256, 6) void fused_offset_transpose_kernel(
    const float* __restrict__ x, const float* __restrict__ wTp,
    float* __restrict__ part, float* __restrict__ xT)
{
    __shared__ float lds[NOFF * WPB * 64];   // 4608 floats = 18.4 KB (max role)
    int bi = blockIdx.x;
    int tid = threadIdx.x;

    if (bi < OFF_BLOCKS) {
        // ------------------- offset-conv role -------------------
        int jx = bi & 255;             // 0..255
        int b = jx & 7;
        int h0 = (jx >> 3) * ROWS;     // 0..62
        int q = bi >> 8;               // 0..3
        int w = tid & 63;
        int wv = __builtin_amdgcn_readfirstlane(tid >> 6);  // 0..3
        int cbase = q * 32 + wv * CPW;

        float acc[NOFF][ROWS];
#pragma unroll
        for (int o = 0; o < NOFF; ++o)
#pragma unroll
            for (int r = 0; r < ROWS; ++r) acc[o][r] = 0.f;

        bool wlo = (w == 0), whi = (w == 63);

#pragma unroll 1
        for (int cc = 0; cc < CPW; ++cc) {
            int c = cbase + cc;
            const float* xp = x + ((size_t)(b * CC + c)) * HW;
            float xc[ROWS + 2], xl[ROWS + 2], xr[ROWS + 2];
#pragma unroll
            for (int rr = 0; rr < ROWS + 2; ++rr) {
                int hh = h0 + rr - 1;          // wave-uniform
                float v = 0.f;
                if ((unsigned)hh < HH) v = xp[hh * WW + w];   // scalar branch
                xc[rr] = v;
                float vl = __shfl_up(v, 1);
                float vr = __shfl_down(v, 1);
                xl[rr] = wlo ? 0.f : vl;
                xr[rr] = whi ? 0.f : vr;
            }
            const float* wrow = wTp + (size_t)c * 9 * WPAD;
#pragma unroll
            for (int jj = 0; jj < 9; ++jj) {
                const int dh = jj / 3, dc = jj % 3;   // compile-time
                const float* wp = wrow + jj * WPAD;   // uniform -> s_load
#pragma unroll
                for (int o = 0; o < NOFF; ++o) {
                    float sw = wp[o];
#pragma unroll
                    for (int r = 0; r < ROWS; ++r) {
                        float xv = (dc == 0) ? xl[r + dh]
                                 : (dc == 1) ? xc[r + dh] : xr[r + dh];
                        acc[o][r] = fmaf(xv, sw, acc[o][r]);
                    }
                }
            }
        }

        // reduce over 4 waves, one row at a time
        for (int r = 0; r < ROWS; ++r) {
#pragma unroll
            for (int o = 0; o < NOFF; ++o)
                lds[(o * WPB + wv) * 64 + w] = acc[o][r];
            __syncthreads();
            for (int item = tid; item < NOFF * 64; item += 256) {
                int o = item >> 6, p = item & 63;
                float s = 0.f;
#pragma unroll
                for (int u = 0; u < WPB; ++u) s += lds[(o * WPB + u) * 64 + p];
                part[((size_t)(q * NOFF + o)) * NPIX + b * HW + (h0 + r) * 64 + p] = s;
            }
            __syncthreads();
        }
    } else {
        // ------------------- transpose role -------------------
        int bt = bi - OFF_BLOCKS;          // 0..4095
        int p0 = (bt & 127) * 32;
        int c0 = ((bt >> 7) & 3) * 32;
        int b  = bt >> 9;
        int tx = tid & 31;
        int ty = tid >> 5;                 // 0..7
        float* tile = lds;                 // needs 32*33 = 1056 floats
#pragma unroll
        for (int i = 0; i < 4; ++i)
            tile[(ty + i * 8) * 33 + tx] =
                x[((size_t)(b * CC + c0 + ty + i * 8)) * HW + p0 + tx];
        __syncthreads();
#pragma unroll
        for (int i = 0; i < 4; ++i)
            xT[((size_t)b * HW + p0 + ty + i * 8) * CC + c0 + tx] =
                tile[tx * 33 + ty + i * 8];
    }
}

// ---------------------------------------------------------------------------
// K2: bilinear sample + tap-weighted sum, float4 channel packing,
// with the quarter-partial reduce + coord transform FUSED into phase A.
// ---------------------------------------------------------------------------
__global__ __launch_bounds__(256) void sample_kernel(
    const float* __restrict__ xT, const float* __restrict__ part,
    const float* __restrict__ offb, const float* __restrict__ wk,
    float* __restrict__ out)
{
    __shared__ float4 recW[144];
    __shared__ int2   recI[144];
    __shared__ float  swkT[K2 * CC];
    __shared__ float  acc_s[16 * 132];

    int j = blockIdx.x;            // 0..2047
    int b = j & 7;
    int rem_base = (j >> 3) * 16;  // within-batch pixel base
    int h  = rem_base >> 6;
    int w0 = rem_base & 63;
    int tid = threadIdx.x;

    for (int i = tid; i < K2 * CC; i += 256) {
        int c = i / 9, t = i - c * 9;
        swkT[t * CC + c] = wk[i];
    }

    if (tid < 144) {
        int slot = tid & 15;
        int tap  = tid >> 4;
        int rem  = rem_base + slot;        // h*64 + w within batch
        int pix  = b * HW + rem;           // global pixel
        float sx = offb[tap], sy = offb[tap + K2];
#pragma unroll
        for (int q2 = 0; q2 < NQ; ++q2) {
            sx += part[((size_t)(q2 * NOFF + tap)) * NPIX + pix];
            sy += part[((size_t)(q2 * NOFF + tap + K2)) * NPIX + pix];
        }
        int ww2 = rem & 63, hh2 = rem >> 6;
        float base_x = -1.f + (2.f / (WW - 1)) * (float)ww2;
        float base_y = -1.f + (2.f / (HH - 1)) * (float)hh2;
        float gx = ((sx + base_x + 1.f) * (float)WW - 1.f) * 0.5f;
        float gy = ((sy + base_y + 1.f) * (float)HH - 1.f) * 0.5f;

        float x0f = floorf(gx), y0f = floorf(gy);
        float wx1 = gx - x0f, wx0 = 1.f - wx1;
        float wy1 = gy - y0f, wy0 = 1.f - wy1;
        int ix0 = (int)x0f, iy0 = (int)y0f;
        int ix1 = ix0 + 1,  iy1 = iy0 + 1;
        float ax0 = ((unsigned)ix0 < WW) ? wx0 : 0.f;
        float ax1 = ((unsigned)ix1 < WW) ? wx1 : 0.f;
        float ay0 = ((unsigned)iy0 < HH) ? wy0 : 0.f;
        float ay1 = ((unsigned)iy1 < HH) ? wy1 : 0.f;
        int cx0 = min(max(ix0, 0), WW - 1), cx1 = min(max(ix1, 0), WW - 1);
        int cy0 = min(max(iy0, 0), HH - 1), cy1 = min(max(iy1, 0), HH - 1);
        int o00 = cy0 * WW + cx0, o10 = cy0 * WW + cx1;
        int o01 = cy1 * WW + cx0, o11 = cy1 * WW + cx1;
        recW[tid] = make_float4(ax0 * ay0, ax1 * ay0, ax0 * ay1, ax1 * ay1);
        recI[tid] = make_int2(o00 | (o10 << 16), o01 | (o11 << 16));
    }
    __syncthreads();

    int c4  = (tid & 31) * 4;
    int sl0 = tid >> 5;

    float4 wk4[K2];
#pragma unroll
    for (int t = 0; t < K2; ++t)
        wk4[t] = *(const float4*)&swkT[t * CC + c4];

    const float* xb = xT + (size_t)b * HW * CC;

#pragma unroll
    for (int pp = 0; pp < 2; ++pp) {
        int slot = pp * 8 + sl0;
        float4 acc = make_float4(0.f, 0.f, 0.f, 0.f);
#pragma unroll
        for (int t = 0; t < K2; ++t) {
            int r = t * 16 + slot;
            float4 wv = recW[r];
            int2   iv = recI[r];
            float4 v00 = *(const float4*)(xb + ((iv.x & 0xFFFF) << 7) + c4);
            float4 v10 = *(const float4*)(xb + ((iv.x >> 16)     << 7) + c4);
            float4 v01 = *(const float4*)(xb + ((iv.y & 0xFFFF) << 7) + c4);
            float4 v11 = *(const float4*)(xb + ((iv.y >> 16)     << 7) + c4);
            float bx0 = fmaf(v00.x, wv.x, fmaf(v10.x, wv.y, fmaf(v01.x, wv.z, v11.x * wv.w)));
            float bx1 = fmaf(v00.y, wv.x, fmaf(v10.y, wv.y, fmaf(v01.y, wv.z, v11.y * wv.w)));
            float bx2 = fmaf(v00.z, wv.x, fmaf(v10.z, wv.y, fmaf(v01.z, wv.z, v11.z * wv.w)));
            float bx3 = fmaf(v00.w, wv.x, fmaf(v10.w, wv.y, fmaf(v01.w, wv.z, v11.w * wv.w)));
            acc.x = fmaf(bx0, wk4[t].x, acc.x);
            acc.y = fmaf(bx1, wk4[t].y, acc.y);
            acc.z = fmaf(bx2, wk4[t].z, acc.z);
            acc.w = fmaf(bx3, wk4[t].w, acc.w);
        }
        *(float4*)&acc_s[slot * 132 + c4] = acc;
    }
    __syncthreads();
#pragma unroll
    for (int r = 0; r < 8; ++r) {
        int cs   = r * 16 + (tid >> 4);
        int wloc = tid & 15;
        out[((size_t)(b * CC + cs)) * HW + h * WW + w0 + wloc] = acc_s[wloc * 132 + cs];
    }
}

// ---------------------------------------------------------------------------
// Fallback (round-1 pipeline, needs only 2.36 MB ws) — defensive only.
// ---------------------------------------------------------------------------
__global__ __launch_bounds__(256) void offset_grid_kernel_fb(
    const float* __restrict__ x, const float* __restrict__ offw,
    const float* __restrict__ offb, float* __restrict__ grid)
{
    int idx = blockIdx.x * blockDim.x + threadIdx.x;
    if (idx >= NPIX) return;
    int w = idx & 63, h = (idx >> 6) & 63, b = idx >> 12;
    float acc[NOFF];
#pragma unroll
    for (int o = 0; o < NOFF; ++o) acc[o] = offb[o];
    for (int c = 0; c < CC; ++c) {
        const float* xp = x + ((size_t)(b * CC + c)) * HW;
        float xv[9];
#pragma unroll
        for (int dh = -1; dh <= 1; ++dh)
#pragma unroll
            for (int dw = -1; dw <= 1; ++dw) {
                int hh = h + dh, ww2 = w + dw;
                float v = 0.f;
                if (hh >= 0 && hh < HH && ww2 >= 0 && ww2 < WW) v = xp[hh * WW + ww2];
                xv[(dh + 1) * 3 + (dw + 1)] = v;
            }
#pragma unroll
        for (int o = 0; o < NOFF; ++o) {
            const float* wp = offw + (size_t)(o * CC + c) * 9;
#pragma unroll
            for (int jj = 0; jj < 9; ++jj) acc[o] = fmaf(xv[jj], wp[jj], acc[o]);
        }
    }
    float base_x = -1.f + (2.f / (WW - 1)) * (float)w;
    float base_y = -1.f + (2.f / (HH - 1)) * (float)h;
#pragma unroll
    for (int t = 0; t < K2; ++t) {
        float gx = ((acc[t]      + base_x + 1.f) * (float)WW - 1.f) * 0.5f;
        float gy = ((acc[K2 + t] + base_y + 1.f) * (float)HH - 1.f) * 0.5f;
        size_t gi = ((((size_t)b * K2 + t) * HH + h) * WW + w) * 2;
        grid[gi] = gx; grid[gi + 1] = gy;
    }
}

__global__ __launch_bounds__(256) void sample_kernel_fb(
    const float* __restrict__ x, const float* __restrict__ grid,
    const float* __restrict__ wk, float* __restrict__ out)
{
    int idx = blockIdx.x * blockDim.x + threadIdx.x;
    if (idx >= BB * CC * HW) return;
    int w = idx & 63, h = (idx >> 6) & 63;
    int c = (idx / HW) & 127, b = idx / (CC * HW);
    const float* xp = x + ((size_t)(b * CC + c)) * HW;
    const float2* gp = (const float2*)grid;
    float acc = 0.f;
#pragma unroll
    for (int t = 0; t < K2; ++t) {
        float2 g = gp[(((size_t)b * K2 + t)) * HW + h * WW + w];
        float gx = g.x, gy = g.y;
        float x0f = floorf(gx), y0f = floorf(gy);
        float wx1 = gx - x0f, wx0 = 1.f - wx1;
        float wy1 = gy - y0f, wy0 = 1.f - wy1;
        int ix0 = (int)x0f, iy0 = (int)y0f;
        int ix1 = ix0 + 1,  iy1 = iy0 + 1;
        float v00 = 0.f, v10 = 0.f, v01 = 0.f, v11 = 0.f;
        if ((unsigned)iy0 < HH) {
            const float* row = xp + (size_t)iy0 * WW;
            if ((unsigned)ix0 < WW) v00 = row[ix0];
            if ((unsigned)ix1 < WW) v10 = row[ix1];
        }
        if ((unsigned)iy1 < HH) {
            const float* row = xp + (size_t)iy1 * WW;
            if ((unsigned)ix0 < WW) v01 = row[ix0];
            if ((unsigned)ix1 < WW) v11 = row[ix1];
        }
        float bil = v00 * (wx0 * wy0) + v10 * (wx1 * wy0)
                  + v01 * (wx0 * wy1) + v11 * (wx1 * wy1);
        acc = fmaf(bil, wk[c * K2 + t], acc);
    }
    out[idx] = acc;
}

extern "C" void kernel_launch(void* const* d_in, const int* in_sizes, int n_in,
                              void* d_out, int out_size, void* d_ws, size_t ws_size,
                              hipStream_t stream) {
    const float* x    = (const float*)d_in[0];
    const float* offw = (const float*)d_in[1];
    const float* offb = (const float*)d_in[2];
    const float* wwk  = (const float*)d_in[3];
    float* out = (float*)d_out;

    const size_t PART_BYTES = (size_t)NQ * NOFF * NPIX * sizeof(float);  // 9.44 MB
    const size_t XT_BYTES   = (size_t)NPIX * CC * sizeof(float);         // 16.8 MB
    const size_t WTP_BYTES  = (size_t)CC * 9 * WPAD * sizeof(float);     // 92 KB
    const size_t NEED = PART_BYTES + XT_BYTES + WTP_BYTES;               // 26.3 MB

    if (ws_size < NEED) {
        float* grid = (float*)d_ws;
        hipLaunchKernelGGL(offset_grid_kernel_fb, dim3(NPIX / 256), dim3(256),
                           0, stream, x, offw, offb, grid);
        hipLaunchKernelGGL(sample_kernel_fb, dim3((BB * CC * HW) / 256), dim3(256),
                           0, stream, x, grid, wwk, out);
        return;
    }

    // ws layout (all live simultaneously): [part 9.44 MB][xT 16.8 MB][wTp 92 KB]
    float* part = (float*)d_ws;
    float* xT   = (float*)((char*)d_ws + PART_BYTES);
    float* wTp  = (float*)((char*)d_ws + PART_BYTES + XT_BYTES);

    hipLaunchKernelGGL(wtrans_kernel, dim3((NOFF * CC * 9 + 255) / 256), dim3(256),
                       0, stream, offw, wTp);
    hipLaunchKernelGGL(fused_offset_transpose_kernel,
                       dim3(OFF_BLOCKS + TR_BLOCKS), dim3(256),
                       0, stream, x, wTp, part, xT);
    hipLaunchKernelGGL(sample_kernel, dim3(NPIX / 16), dim3(256),
                       0, stream, xT, part, offb, wwk, out);
}